// Round 5
// baseline (992.252 us; speedup 1.0000x reference)
//
#include <hip/hip_runtime.h>
#include <math.h>

#define D 64

// ---- helpers ------------------------------------------------------------

__device__ __forceinline__ float4 f4scale(float4 a, float b) {
    return make_float4(a.x * b, a.y * b, a.z * b, a.w * b);
}

__device__ __forceinline__ unsigned int bf16_rne(float x) {
    unsigned int u = __float_as_uint(x);
    u += 0x7fffu + ((u >> 16) & 1u);
    return u >> 16;
}

__device__ __forceinline__ uint4 pack_bf16x8(const float* v) {
    uint4 p;
    p.x = bf16_rne(v[0]) | (bf16_rne(v[1]) << 16);
    p.y = bf16_rne(v[2]) | (bf16_rne(v[3]) << 16);
    p.z = bf16_rne(v[4]) | (bf16_rne(v[5]) << 16);
    p.w = bf16_rne(v[6]) | (bf16_rne(v[7]) << 16);
    return p;
}

__device__ __forceinline__ void acc_bf16x8(uint4 p, float* a) {
    a[0] += __uint_as_float(p.x << 16);
    a[1] += __uint_as_float(p.x & 0xffff0000u);
    a[2] += __uint_as_float(p.y << 16);
    a[3] += __uint_as_float(p.y & 0xffff0000u);
    a[4] += __uint_as_float(p.z << 16);
    a[5] += __uint_as_float(p.z & 0xffff0000u);
    a[6] += __uint_as_float(p.w << 16);
    a[7] += __uint_as_float(p.w & 0xffff0000u);
}

// ---- CSR build ----------------------------------------------------------

__global__ void count_edges(const int* __restrict__ dst, int* __restrict__ counts, int E) {
    int e = blockIdx.x * blockDim.x + threadIdx.x;
    if (e < E) atomicAdd(&counts[dst[e]], 1);
}

__global__ void block_sums(const int* __restrict__ counts, int* __restrict__ bsum, int n) {
    int base = blockIdx.x * 1024;
    int t = threadIdx.x;
    int v = 0;
    #pragma unroll
    for (int j = 0; j < 4; ++j) {
        int i = base + t + j * 256;
        if (i < n) v += counts[i];
    }
    #pragma unroll
    for (int m = 32; m >= 1; m >>= 1) v += __shfl_xor(v, m, 64);
    __shared__ int ws[4];
    if ((t & 63) == 0) ws[t >> 6] = v;
    __syncthreads();
    if (t == 0) bsum[blockIdx.x] = ws[0] + ws[1] + ws[2] + ws[3];
}

__global__ void scan_bsums(int* __restrict__ bsum, int nb, int* __restrict__ offsets, int n) {
    __shared__ int tmp[1024];
    int t = threadIdx.x;
    int v = (t < nb) ? bsum[t] : 0;
    tmp[t] = v;
    __syncthreads();
    for (int off = 1; off < 1024; off <<= 1) {
        int x = (t >= off) ? tmp[t - off] : 0;
        __syncthreads();
        tmp[t] += x;
        __syncthreads();
    }
    if (t < nb) bsum[t] = tmp[t] - v;
    if (t == 1023) offsets[n] = tmp[1023];
}

__global__ void scan_block(const int* __restrict__ counts, const int* __restrict__ bsum,
                           int* __restrict__ offsets, float* __restrict__ norm, int n) {
    __shared__ int tmp[1024];
    int base = blockIdx.x * 1024;
    int t = threadIdx.x;
    int i = base + t;
    int v = (i < n) ? counts[i] : 0;
    tmp[t] = v;
    __syncthreads();
    for (int off = 1; off < 1024; off <<= 1) {
        int x = (t >= off) ? tmp[t - off] : 0;
        __syncthreads();
        tmp[t] += x;
        __syncthreads();
    }
    if (i < n) {
        offsets[i] = bsum[blockIdx.x] + tmp[t] - v;
        norm[i] = rsqrtf((float)(v > 1 ? v : 1));
    }
}

// Pass A: append each edge to its coarse bucket (128 dst-nodes per bucket).
// Bucket region in ebuf = [offsets[b*128], offsets[(b+1)*128]) — contiguous
// appends give line-local writes (vs 64B writeback per 4B in flat fill).
__global__ void bucket_edges(const int* __restrict__ src, const int* __restrict__ dst,
                             const int* __restrict__ offsets, int* __restrict__ bcur,
                             unsigned int* __restrict__ ebuf, int E) {
    int e = blockIdx.x * blockDim.x + threadIdx.x;
    if (e < E) {
        int v = dst[e];
        int b = v >> 7;
        int pos = atomicAdd(&bcur[b], 1);
        int rbeg = offsets[b << 7];          // 782 hot values, L2-resident
        ebuf[rbeg + pos] = (unsigned int)src[e] | ((unsigned int)(v & 127) << 20);
    }
}

// Pass B: one block per bucket; node cursors in LDS; every csr line written
// by exactly one block (reads coalesced, writes line-local).
__global__ void fill_from_buckets(const unsigned int* __restrict__ ebuf,
                                  const int* __restrict__ offsets,
                                  int* __restrict__ csr, int N) {
    __shared__ int offs[129];
    __shared__ int cur[128];
    int base = blockIdx.x << 7;
    int nn = N - base; if (nn > 128) nn = 128;
    int t = threadIdx.x;
    if (t <= nn) offs[t] = offsets[base + t];
    if (t < 128) cur[t] = 0;
    __syncthreads();
    int rbeg = offs[0], rend = offs[nn];
    for (int i = rbeg + t; i < rend; i += 256) {
        unsigned int u = ebuf[i];
        int srcv = (int)(u & 0xFFFFFu);
        int dlo  = (int)(u >> 20);
        int pos = atomicAdd(&cur[dlo], 1);
        csr[offs[dlo] + pos] = srcv;
    }
}

// ---- hop 0: out = sigmoid(f.s)*f ; g0 = bf16(f*norm) --------------------

__global__ void hop0(const float4* __restrict__ feat, const float* __restrict__ s,
                     const float* __restrict__ norm, uint4* __restrict__ g,
                     float4* __restrict__ out, int n) {
    int t = blockIdx.x * blockDim.x + threadIdx.x;
    int node = t >> 3;
    int l = t & 7;
    if (node >= n) return;
    float4 f0 = feat[node * 16 + 2 * l];
    float4 f1 = feat[node * 16 + 2 * l + 1];
    const float4* s4 = (const float4*)s;
    float4 a = s4[2 * l], b = s4[2 * l + 1];
    float dot = f0.x * a.x + f0.y * a.y + f0.z * a.z + f0.w * a.w
              + f1.x * b.x + f1.y * b.y + f1.z * b.z + f1.w * b.w;
    #pragma unroll
    for (int m = 1; m <= 4; m <<= 1) dot += __shfl_xor(dot, m, 64);
    float sig = 1.0f / (1.0f + expf(-dot));
    out[node * 16 + 2 * l]     = f4scale(f0, sig);
    out[node * 16 + 2 * l + 1] = f4scale(f1, sig);
    float nv = norm[node];
    float v[8] = {f0.x * nv, f0.y * nv, f0.z * nv, f0.w * nv,
                  f1.x * nv, f1.y * nv, f1.z * nv, f1.w * nv};
    g[node * 8 + l] = pack_bf16x8(v);
}

// ---- hop t: gather-SpMM (bf16 rows) + fused attention-pool epilogue -----
// wave per node. lane = 8*g + l. Divergence-free shuffles: trip count is
// wave-uniform, every __shfl runs with all 64 lanes active, in-range source.

__global__ void spmm_hop(const uint4* __restrict__ gin, const int* __restrict__ offsets,
                         const int* __restrict__ csr, const float* __restrict__ norm,
                         const float* __restrict__ s, uint4* __restrict__ gout,
                         float4* __restrict__ out, int n) {
    int lane = threadIdx.x & 63;
    int node = blockIdx.x * 4 + (threadIdx.x >> 6);
    if (node >= n) return;
    int g = lane >> 3;
    int l = lane & 7;
    int beg = offsets[node], end = offsets[node + 1];
    int deg = end - beg;
    int dcap = deg < 64 ? deg : 64;
    int idx = (lane < dcap) ? csr[beg + lane] : 0;

    float acc[8] = {0.f, 0.f, 0.f, 0.f, 0.f, 0.f, 0.f, 0.f};
    int trips = (dcap + 7) >> 3;     // wave-uniform (0..8)
    int j = 0;
    for (; j + 2 <= trips; j += 2) {
        int e0 = g + (j << 3);
        int e1 = e0 + 8;
        int u0 = __shfl(idx, e0, 64);
        int u1 = __shfl(idx, e1, 64);
        uint4 p0 = gin[(size_t)u0 * 8 + l];
        uint4 p1 = gin[(size_t)u1 * 8 + l];
        if (e0 < dcap) acc_bf16x8(p0, acc);
        if (e1 < dcap) acc_bf16x8(p1, acc);
    }
    if (j < trips) {
        int e0 = g + (j << 3);
        int u0 = __shfl(idx, e0, 64);
        uint4 p0 = gin[(size_t)u0 * 8 + l];
        if (e0 < dcap) acc_bf16x8(p0, acc);
    }
    for (int i = beg + 64 + g; i < end; i += 8) {   // deg>64: essentially never
        acc_bf16x8(gin[(size_t)csr[i] * 8 + l], acc);
    }

    #pragma unroll
    for (int m = 8; m <= 32; m <<= 1) {
        #pragma unroll
        for (int jj = 0; jj < 8; ++jj) acc[jj] += __shfl_xor(acc[jj], m, 64);
    }

    float nv = norm[node];
    float h[8];
    #pragma unroll
    for (int jj = 0; jj < 8; ++jj) h[jj] = acc[jj] * nv;

    const float4* s4 = (const float4*)s;
    float4 a = s4[2 * l], b = s4[2 * l + 1];
    float dot = h[0] * a.x + h[1] * a.y + h[2] * a.z + h[3] * a.w
              + h[4] * b.x + h[5] * b.y + h[6] * b.z + h[7] * b.w;
    #pragma unroll
    for (int m = 1; m <= 4; m <<= 1) dot += __shfl_xor(dot, m, 64);
    float sig = 1.0f / (1.0f + expf(-dot));

    if (g == 0) {
        float gv[8];
        #pragma unroll
        for (int jj = 0; jj < 8; ++jj) gv[jj] = h[jj] * nv;
        gout[node * 8 + l] = pack_bf16x8(gv);
        float4 o0 = out[node * 16 + 2 * l];
        float4 o1 = out[node * 16 + 2 * l + 1];
        o0.x += sig * h[0]; o0.y += sig * h[1]; o0.z += sig * h[2]; o0.w += sig * h[3];
        o1.x += sig * h[4]; o1.y += sig * h[5]; o1.z += sig * h[6]; o1.w += sig * h[7];
        out[node * 16 + 2 * l]     = o0;
        out[node * 16 + 2 * l + 1] = o1;
    }
}

// ---- launcher -----------------------------------------------------------

extern "C" void kernel_launch(void* const* d_in, const int* in_sizes, int n_in,
                              void* d_out, int out_size, void* d_ws, size_t ws_size,
                              hipStream_t stream) {
    const float* feat = (const float*)d_in[0];
    const float* s    = (const float*)d_in[1];
    const int*   src  = (const int*)d_in[2];
    const int*   dst  = (const int*)d_in[3];
    const int K = 10;

    int N = in_sizes[0] / D;
    int E = in_sizes[2];
    int nchunks = (N + 1023) / 1024;   // 98 for N=100000 (<= 1024 required)
    int NB = (N + 127) >> 7;           // 782 coarse buckets (128 nodes each)

    // workspace layout
    int*   counts  = (int*)d_ws;               // N
    int*   bcur    = counts + N;               // 1024 (bucket cursors)
    int*   offsets = bcur + 1024;              // N+1
    int*   csr     = offsets + (N + 1);        // E
    float* norm    = (float*)(csr + E);        // N
    int*   bsum    = (int*)(norm + N);         // nchunks
    uintptr_t p = (uintptr_t)(bsum + nchunks);
    p = (p + 255) & ~(uintptr_t)255;
    uint4* g0 = (uint4*)p;                     // N*8 uint4 (bf16 rows)
    uint4* g1 = g0 + (size_t)N * 8;            // N*8 uint4
    // ebuf (E u32 = 6.4MB) aliases g1 (12.8MB): dead before first spmm writes g1
    unsigned int* ebuf = (unsigned int*)g1;

    hipMemsetAsync(counts, 0, sizeof(int) * ((size_t)N + 1024), stream);  // counts + bcur

    count_edges<<<(E + 255) / 256, 256, 0, stream>>>(dst, counts, E);
    block_sums<<<nchunks, 256, 0, stream>>>(counts, bsum, N);
    scan_bsums<<<1, 1024, 0, stream>>>(bsum, nchunks, offsets, N);
    scan_block<<<nchunks, 1024, 0, stream>>>(counts, bsum, offsets, norm, N);
    bucket_edges<<<(E + 255) / 256, 256, 0, stream>>>(src, dst, offsets, bcur, ebuf, E);
    fill_from_buckets<<<NB, 256, 0, stream>>>(ebuf, offsets, csr, N);

    hop0<<<(N * 8 + 255) / 256, 256, 0, stream>>>(
        (const float4*)feat, s, norm, g0, (float4*)d_out, N);

    uint4* gin = g0; uint4* gout = g1;
    for (int t = 0; t < K; ++t) {
        spmm_hop<<<(N + 3) / 4, 256, 0, stream>>>(
            gin, offsets, csr, norm, s, gout, (float4*)d_out, N);
        uint4* tmp = gin; gin = gout; gout = tmp;
    }
}

// Round 6
// 673.399 us; speedup vs baseline: 1.4735x; 1.4735x over previous
//
#include <hip/hip_runtime.h>
#include <math.h>

#define D 64

// ---- helpers ------------------------------------------------------------

__device__ __forceinline__ float4 f4scale(float4 a, float b) {
    return make_float4(a.x * b, a.y * b, a.z * b, a.w * b);
}

__device__ __forceinline__ unsigned int bf16_rne(float x) {
    unsigned int u = __float_as_uint(x);
    u += 0x7fffu + ((u >> 16) & 1u);
    return u >> 16;
}

__device__ __forceinline__ uint4 pack_bf16x8(const float* v) {
    uint4 p;
    p.x = bf16_rne(v[0]) | (bf16_rne(v[1]) << 16);
    p.y = bf16_rne(v[2]) | (bf16_rne(v[3]) << 16);
    p.z = bf16_rne(v[4]) | (bf16_rne(v[5]) << 16);
    p.w = bf16_rne(v[6]) | (bf16_rne(v[7]) << 16);
    return p;
}

__device__ __forceinline__ void acc_bf16x8(uint4 p, float* a) {
    a[0] += __uint_as_float(p.x << 16);
    a[1] += __uint_as_float(p.x & 0xffff0000u);
    a[2] += __uint_as_float(p.y << 16);
    a[3] += __uint_as_float(p.y & 0xffff0000u);
    a[4] += __uint_as_float(p.z << 16);
    a[5] += __uint_as_float(p.z & 0xffff0000u);
    a[6] += __uint_as_float(p.w << 16);
    a[7] += __uint_as_float(p.w & 0xffff0000u);
}

// ---- CSR build ----------------------------------------------------------

__global__ void count_edges(const int* __restrict__ dst, int* __restrict__ counts, int E) {
    int e = blockIdx.x * blockDim.x + threadIdx.x;
    if (e < E) atomicAdd(&counts[dst[e]], 1);
}

__global__ void block_sums(const int* __restrict__ counts, int* __restrict__ bsum, int n) {
    int base = blockIdx.x * 1024;
    int t = threadIdx.x;
    int v = 0;
    #pragma unroll
    for (int j = 0; j < 4; ++j) {
        int i = base + t + j * 256;
        if (i < n) v += counts[i];
    }
    #pragma unroll
    for (int m = 32; m >= 1; m >>= 1) v += __shfl_xor(v, m, 64);
    __shared__ int ws[4];
    if ((t & 63) == 0) ws[t >> 6] = v;
    __syncthreads();
    if (t == 0) bsum[blockIdx.x] = ws[0] + ws[1] + ws[2] + ws[3];
}

__global__ void scan_bsums(int* __restrict__ bsum, int nb, int* __restrict__ offsets, int n) {
    __shared__ int tmp[1024];
    int t = threadIdx.x;
    int v = (t < nb) ? bsum[t] : 0;
    tmp[t] = v;
    __syncthreads();
    for (int off = 1; off < 1024; off <<= 1) {
        int x = (t >= off) ? tmp[t - off] : 0;
        __syncthreads();
        tmp[t] += x;
        __syncthreads();
    }
    if (t < nb) bsum[t] = tmp[t] - v;
    if (t == 1023) offsets[n] = tmp[1023];
}

__global__ void scan_block(const int* __restrict__ counts, const int* __restrict__ bsum,
                           int* __restrict__ offsets, float* __restrict__ norm, int n) {
    __shared__ int tmp[1024];
    int base = blockIdx.x * 1024;
    int t = threadIdx.x;
    int i = base + t;
    int v = (i < n) ? counts[i] : 0;
    tmp[t] = v;
    __syncthreads();
    for (int off = 1; off < 1024; off <<= 1) {
        int x = (t >= off) ? tmp[t - off] : 0;
        __syncthreads();
        tmp[t] += x;
        __syncthreads();
    }
    if (i < n) {
        offsets[i] = bsum[blockIdx.x] + tmp[t] - v;
        norm[i] = rsqrtf((float)(v > 1 ? v : 1));
    }
}

// XCD-filtered fill: consecutive blocks round-robin over the 8 XCDs
// (heuristic; wrong mapping costs only speed). Block with xcd=blockIdx&7
// commits only edges whose dst partition (dst>>11)&7 == xcd, so every
// csr cache line (16 entries ~ one node region) has XCD-local writers:
// no cross-XCD line ping-pong, writeback ~= payload (6.4MB, not 107MB).
// Per-node cursors keep atomic contention low (~16 per address).
#define FILL_U 8   // edges per thread per pass
__global__ void fill_csr_xcd(const int* __restrict__ src, const int* __restrict__ dst,
                             const int* __restrict__ offsets, int* __restrict__ cursor,
                             int* __restrict__ csr, int E) {
    int xcd = blockIdx.x & 7;
    int chunk = blockIdx.x >> 3;
    int base = chunk * (256 * FILL_U) + (int)threadIdx.x;
    #pragma unroll
    for (int j = 0; j < FILL_U; ++j) {
        int e = base + j * 256;
        if (e < E) {
            int v = dst[e];
            if (((v >> 11) & 7) == xcd) {
                int pos = atomicAdd(&cursor[v], 1);
                csr[offsets[v] + pos] = src[e];
            }
        }
    }
}

// ---- hop 0: out = sigmoid(f.s)*f ; g0 = bf16(f*norm) --------------------

__global__ void hop0(const float4* __restrict__ feat, const float* __restrict__ s,
                     const float* __restrict__ norm, uint4* __restrict__ g,
                     float4* __restrict__ out, int n) {
    int t = blockIdx.x * blockDim.x + threadIdx.x;
    int node = t >> 3;
    int l = t & 7;
    if (node >= n) return;
    float4 f0 = feat[node * 16 + 2 * l];
    float4 f1 = feat[node * 16 + 2 * l + 1];
    const float4* s4 = (const float4*)s;
    float4 a = s4[2 * l], b = s4[2 * l + 1];
    float dot = f0.x * a.x + f0.y * a.y + f0.z * a.z + f0.w * a.w
              + f1.x * b.x + f1.y * b.y + f1.z * b.z + f1.w * b.w;
    #pragma unroll
    for (int m = 1; m <= 4; m <<= 1) dot += __shfl_xor(dot, m, 64);
    float sig = 1.0f / (1.0f + expf(-dot));
    out[node * 16 + 2 * l]     = f4scale(f0, sig);
    out[node * 16 + 2 * l + 1] = f4scale(f1, sig);
    float nv = norm[node];
    float v[8] = {f0.x * nv, f0.y * nv, f0.z * nv, f0.w * nv,
                  f1.x * nv, f1.y * nv, f1.z * nv, f1.w * nv};
    g[node * 8 + l] = pack_bf16x8(v);
}

// ---- hop t: gather-SpMM (bf16 rows) + fused attention-pool epilogue -----
// wave per node. lane = 8*g + l. Divergence-free shuffles: trip count is
// wave-uniform, every __shfl runs with all 64 lanes active, in-range source.

__global__ void spmm_hop(const uint4* __restrict__ gin, const int* __restrict__ offsets,
                         const int* __restrict__ csr, const float* __restrict__ norm,
                         const float* __restrict__ s, uint4* __restrict__ gout,
                         float4* __restrict__ out, int n) {
    int lane = threadIdx.x & 63;
    int node = blockIdx.x * 4 + (threadIdx.x >> 6);
    if (node >= n) return;
    int g = lane >> 3;
    int l = lane & 7;
    int beg = offsets[node], end = offsets[node + 1];
    int deg = end - beg;
    int dcap = deg < 64 ? deg : 64;
    int idx = (lane < dcap) ? csr[beg + lane] : 0;

    float acc[8] = {0.f, 0.f, 0.f, 0.f, 0.f, 0.f, 0.f, 0.f};
    int trips = (dcap + 7) >> 3;     // wave-uniform (0..8)
    int j = 0;
    for (; j + 2 <= trips; j += 2) {
        int e0 = g + (j << 3);
        int e1 = e0 + 8;
        int u0 = __shfl(idx, e0, 64);
        int u1 = __shfl(idx, e1, 64);
        uint4 p0 = gin[(size_t)u0 * 8 + l];
        uint4 p1 = gin[(size_t)u1 * 8 + l];
        if (e0 < dcap) acc_bf16x8(p0, acc);
        if (e1 < dcap) acc_bf16x8(p1, acc);
    }
    if (j < trips) {
        int e0 = g + (j << 3);
        int u0 = __shfl(idx, e0, 64);
        uint4 p0 = gin[(size_t)u0 * 8 + l];
        if (e0 < dcap) acc_bf16x8(p0, acc);
    }
    for (int i = beg + 64 + g; i < end; i += 8) {   // deg>64: essentially never
        acc_bf16x8(gin[(size_t)csr[i] * 8 + l], acc);
    }

    #pragma unroll
    for (int m = 8; m <= 32; m <<= 1) {
        #pragma unroll
        for (int jj = 0; jj < 8; ++jj) acc[jj] += __shfl_xor(acc[jj], m, 64);
    }

    float nv = norm[node];
    float h[8];
    #pragma unroll
    for (int jj = 0; jj < 8; ++jj) h[jj] = acc[jj] * nv;

    const float4* s4 = (const float4*)s;
    float4 a = s4[2 * l], b = s4[2 * l + 1];
    float dot = h[0] * a.x + h[1] * a.y + h[2] * a.z + h[3] * a.w
              + h[4] * b.x + h[5] * b.y + h[6] * b.z + h[7] * b.w;
    #pragma unroll
    for (int m = 1; m <= 4; m <<= 1) dot += __shfl_xor(dot, m, 64);
    float sig = 1.0f / (1.0f + expf(-dot));

    if (g == 0) {
        float gv[8];
        #pragma unroll
        for (int jj = 0; jj < 8; ++jj) gv[jj] = h[jj] * nv;
        gout[node * 8 + l] = pack_bf16x8(gv);
        float4 o0 = out[node * 16 + 2 * l];
        float4 o1 = out[node * 16 + 2 * l + 1];
        o0.x += sig * h[0]; o0.y += sig * h[1]; o0.z += sig * h[2]; o0.w += sig * h[3];
        o1.x += sig * h[4]; o1.y += sig * h[5]; o1.z += sig * h[6]; o1.w += sig * h[7];
        out[node * 16 + 2 * l]     = o0;
        out[node * 16 + 2 * l + 1] = o1;
    }
}

// ---- launcher -----------------------------------------------------------

extern "C" void kernel_launch(void* const* d_in, const int* in_sizes, int n_in,
                              void* d_out, int out_size, void* d_ws, size_t ws_size,
                              hipStream_t stream) {
    const float* feat = (const float*)d_in[0];
    const float* s    = (const float*)d_in[1];
    const int*   src  = (const int*)d_in[2];
    const int*   dst  = (const int*)d_in[3];
    const int K = 10;

    int N = in_sizes[0] / D;
    int E = in_sizes[2];
    int nchunks = (N + 1023) / 1024;   // 98 for N=100000 (<= 1024 required)

    // workspace layout
    int*   counts  = (int*)d_ws;               // N
    int*   cursor  = counts + N;               // N
    int*   offsets = cursor + N;               // N+1
    int*   csr     = offsets + (N + 1);        // E
    float* norm    = (float*)(csr + E);        // N
    int*   bsum    = (int*)(norm + N);         // nchunks
    uintptr_t p = (uintptr_t)(bsum + nchunks);
    p = (p + 255) & ~(uintptr_t)255;
    uint4* g0 = (uint4*)p;                     // N*8 uint4 (bf16 rows)
    uint4* g1 = g0 + (size_t)N * 8;            // N*8 uint4

    hipMemsetAsync(counts, 0, sizeof(int) * 2 * (size_t)N, stream);  // counts + cursor

    count_edges<<<(E + 255) / 256, 256, 0, stream>>>(dst, counts, E);
    block_sums<<<nchunks, 256, 0, stream>>>(counts, bsum, N);
    scan_bsums<<<1, 1024, 0, stream>>>(bsum, nchunks, offsets, N);
    scan_block<<<nchunks, 1024, 0, stream>>>(counts, bsum, offsets, norm, N);
    {
        int chunk_elems = 256 * FILL_U;
        int nchunk = (E + chunk_elems - 1) / chunk_elems;
        fill_csr_xcd<<<nchunk * 8, 256, 0, stream>>>(src, dst, offsets, cursor, csr, E);
    }

    hop0<<<(N * 8 + 255) / 256, 256, 0, stream>>>(
        (const float4*)feat, s, norm, g0, (float4*)d_out, N);

    uint4* gin = g0; uint4* gout = g1;
    for (int t = 0; t < K; ++t) {
        spmm_hop<<<(N + 3) / 4, 256, 0, stream>>>(
            gin, offsets, csr, norm, s, gout, (float4*)d_out, N);
        uint4* tmp = gin; gin = gout; gout = tmp;
    }
}

// Round 7
// 660.671 us; speedup vs baseline: 1.5019x; 1.0193x over previous
//
#include <hip/hip_runtime.h>
#include <math.h>

#define D 64
#define RB 2048          // nodes per range (temporal write-cluster unit)
#define EB 2048          // edges per partition block

// ---- helpers ------------------------------------------------------------

__device__ __forceinline__ float4 f4scale(float4 a, float b) {
    return make_float4(a.x * b, a.y * b, a.z * b, a.w * b);
}

__device__ __forceinline__ unsigned int bf16_rne(float x) {
    unsigned int u = __float_as_uint(x);
    u += 0x7fffu + ((u >> 16) & 1u);
    return u >> 16;
}

__device__ __forceinline__ uint4 pack_bf16x8(const float* v) {
    uint4 p;
    p.x = bf16_rne(v[0]) | (bf16_rne(v[1]) << 16);
    p.y = bf16_rne(v[2]) | (bf16_rne(v[3]) << 16);
    p.z = bf16_rne(v[4]) | (bf16_rne(v[5]) << 16);
    p.w = bf16_rne(v[6]) | (bf16_rne(v[7]) << 16);
    return p;
}

__device__ __forceinline__ void acc_bf16x8(uint4 p, float* a) {
    a[0] += __uint_as_float(p.x << 16);
    a[1] += __uint_as_float(p.x & 0xffff0000u);
    a[2] += __uint_as_float(p.y << 16);
    a[3] += __uint_as_float(p.y & 0xffff0000u);
    a[4] += __uint_as_float(p.z << 16);
    a[5] += __uint_as_float(p.z & 0xffff0000u);
    a[6] += __uint_as_float(p.w << 16);
    a[7] += __uint_as_float(p.w & 0xffff0000u);
}

// ---- degree count + offsets/norm ----------------------------------------

__global__ void count_edges(const int* __restrict__ dst, int* __restrict__ counts, int E) {
    int e = blockIdx.x * blockDim.x + threadIdx.x;
    if (e < E) atomicAdd(&counts[dst[e]], 1);
}

__global__ void block_sums(const int* __restrict__ counts, int* __restrict__ bsum, int n) {
    int base = blockIdx.x * 1024;
    int t = threadIdx.x;
    int v = 0;
    #pragma unroll
    for (int j = 0; j < 4; ++j) {
        int i = base + t + j * 256;
        if (i < n) v += counts[i];
    }
    #pragma unroll
    for (int m = 32; m >= 1; m >>= 1) v += __shfl_xor(v, m, 64);
    __shared__ int ws[4];
    if ((t & 63) == 0) ws[t >> 6] = v;
    __syncthreads();
    if (t == 0) bsum[blockIdx.x] = ws[0] + ws[1] + ws[2] + ws[3];
}

__global__ void scan_bsums(int* __restrict__ bsum, int nb, int* __restrict__ offsets, int n) {
    __shared__ int tmp[1024];
    int t = threadIdx.x;
    int v = (t < nb) ? bsum[t] : 0;
    tmp[t] = v;
    __syncthreads();
    for (int off = 1; off < 1024; off <<= 1) {
        int x = (t >= off) ? tmp[t - off] : 0;
        __syncthreads();
        tmp[t] += x;
        __syncthreads();
    }
    if (t < nb) bsum[t] = tmp[t] - v;
    if (offsets && t == 1023) offsets[n] = tmp[1023];
}

__global__ void scan_block(const int* __restrict__ counts, const int* __restrict__ bsum,
                           int* __restrict__ offsets, float* __restrict__ norm, int n) {
    __shared__ int tmp[1024];
    int base = blockIdx.x * 1024;
    int t = threadIdx.x;
    int i = base + t;
    int v = (i < n) ? counts[i] : 0;
    tmp[t] = v;
    __syncthreads();
    for (int off = 1; off < 1024; off <<= 1) {
        int x = (t >= off) ? tmp[t - off] : 0;
        __syncthreads();
        tmp[t] += x;
        __syncthreads();
    }
    if (i < n) {
        offsets[i] = bsum[blockIdx.x] + tmp[t] - v;
        norm[i] = rsqrtf((float)(v > 1 ? v : 1));
    }
}

// generic scan kernels (for the 49x782 multisplit counter array)
__global__ void gen_scan2(const int* __restrict__ arr, const int* __restrict__ bsum,
                          int* __restrict__ out, int n) {
    __shared__ int tmp[1024];
    int base = blockIdx.x * 1024;
    int t = threadIdx.x;
    int i = base + t;
    int v = (i < n) ? arr[i] : 0;
    tmp[t] = v;
    __syncthreads();
    for (int off = 1; off < 1024; off <<= 1) {
        int x = (t >= off) ? tmp[t - off] : 0;
        __syncthreads();
        tmp[t] += x;
        __syncthreads();
    }
    if (i < n) out[i] = bsum[blockIdx.x] + tmp[t] - v;
}

// ---- multisplit CSR build (no global atomics, line-local writes) --------
// NR = number of 2048-node ranges, NBLK = number of 2048-edge blocks.

// phase 1: per-(block,range) histogram via LDS atomics
__global__ void countA(const int* __restrict__ dst, int* __restrict__ countsA_T,
                       int E, int NR, int NBLK) {
    __shared__ int hist[64];
    int t = threadIdx.x;
    if (t < 64) hist[t] = 0;
    __syncthreads();
    int base = blockIdx.x * EB + t;
    #pragma unroll
    for (int j = 0; j < EB / 256; ++j) {
        int e = base + j * 256;
        if (e < E) atomicAdd(&hist[dst[e] >> 11], 1);
    }
    __syncthreads();
    if (t < NR) countsA_T[t * NBLK + blockIdx.x] = hist[t];
}

// phase 3: place (src | dst_local<<17) into range-partitioned ebuf2.
// LDS cursors seeded from the scanned bases -> zero global atomics;
// each (block,range) writes one contiguous ~run.
__global__ void passA2(const int* __restrict__ src, const int* __restrict__ dst,
                       const int* __restrict__ baseA, unsigned int* __restrict__ ebuf2,
                       int E, int NR, int NBLK) {
    __shared__ int cur[64];
    int t = threadIdx.x;
    if (t < NR) cur[t] = baseA[t * NBLK + blockIdx.x];
    __syncthreads();
    int base = blockIdx.x * EB + t;
    #pragma unroll
    for (int j = 0; j < EB / 256; ++j) {
        int e = base + j * 256;
        if (e < E) {
            int v = dst[e];
            int rg = v >> 11;
            int pos = atomicAdd(&cur[rg], 1);
            ebuf2[pos] = (unsigned int)src[e] | ((unsigned int)(v & (RB - 1)) << 17);
        }
    }
}

// phase 4: one block per range; node cursors in LDS; every csr line written
// by exactly ONE block within a tight window -> writeback ~= payload.
__global__ void passB(const unsigned int* __restrict__ ebuf2,
                      const int* __restrict__ offsets,
                      int* __restrict__ csr, int N) {
    __shared__ int offs[RB + 1];
    __shared__ int cur[RB];
    int nb0 = blockIdx.x << 11;
    int nn = N - nb0; if (nn > RB) nn = RB;
    int t = threadIdx.x;
    for (int i = t; i <= nn; i += 1024) offs[i] = offsets[nb0 + i];
    for (int i = t; i < RB; i += 1024) cur[i] = 0;
    __syncthreads();
    int r0 = offs[0], r1 = offs[nn];
    for (int i = r0 + t; i < r1; i += 1024) {
        unsigned int u = ebuf2[i];
        int srcv = (int)(u & 0x1FFFFu);
        int dlo  = (int)(u >> 17);
        int pos = atomicAdd(&cur[dlo], 1);
        csr[offs[dlo] + pos] = srcv;
    }
}

// ---- hop 0: out = sigmoid(f.s)*f ; g0 = bf16(f*norm) --------------------

__global__ void hop0(const float4* __restrict__ feat, const float* __restrict__ s,
                     const float* __restrict__ norm, uint4* __restrict__ g,
                     float4* __restrict__ out, int n) {
    int t = blockIdx.x * blockDim.x + threadIdx.x;
    int node = t >> 3;
    int l = t & 7;
    if (node >= n) return;
    float4 f0 = feat[node * 16 + 2 * l];
    float4 f1 = feat[node * 16 + 2 * l + 1];
    const float4* s4 = (const float4*)s;
    float4 a = s4[2 * l], b = s4[2 * l + 1];
    float dot = f0.x * a.x + f0.y * a.y + f0.z * a.z + f0.w * a.w
              + f1.x * b.x + f1.y * b.y + f1.z * b.z + f1.w * b.w;
    #pragma unroll
    for (int m = 1; m <= 4; m <<= 1) dot += __shfl_xor(dot, m, 64);
    float sig = 1.0f / (1.0f + expf(-dot));
    out[node * 16 + 2 * l]     = f4scale(f0, sig);
    out[node * 16 + 2 * l + 1] = f4scale(f1, sig);
    float nv = norm[node];
    float v[8] = {f0.x * nv, f0.y * nv, f0.z * nv, f0.w * nv,
                  f1.x * nv, f1.y * nv, f1.z * nv, f1.w * nv};
    g[node * 8 + l] = pack_bf16x8(v);
}

// ---- hop t: gather-SpMM (bf16 rows) + fused attention-pool epilogue -----
// wave per node. lane = 8*g + l. Divergence-free shuffles (see r4 notes).

__global__ void spmm_hop(const uint4* __restrict__ gin, const int* __restrict__ offsets,
                         const int* __restrict__ csr, const float* __restrict__ norm,
                         const float* __restrict__ s, uint4* __restrict__ gout,
                         float4* __restrict__ out, int n) {
    int lane = threadIdx.x & 63;
    int node = blockIdx.x * 4 + (threadIdx.x >> 6);
    if (node >= n) return;
    int g = lane >> 3;
    int l = lane & 7;
    int beg = offsets[node], end = offsets[node + 1];
    int deg = end - beg;
    int dcap = deg < 64 ? deg : 64;
    int idx = (lane < dcap) ? csr[beg + lane] : 0;

    float acc[8] = {0.f, 0.f, 0.f, 0.f, 0.f, 0.f, 0.f, 0.f};
    int trips = (dcap + 7) >> 3;     // wave-uniform (0..8)
    int j = 0;
    for (; j + 2 <= trips; j += 2) {
        int e0 = g + (j << 3);
        int e1 = e0 + 8;
        int u0 = __shfl(idx, e0, 64);
        int u1 = __shfl(idx, e1, 64);
        uint4 p0 = gin[(size_t)u0 * 8 + l];
        uint4 p1 = gin[(size_t)u1 * 8 + l];
        if (e0 < dcap) acc_bf16x8(p0, acc);
        if (e1 < dcap) acc_bf16x8(p1, acc);
    }
    if (j < trips) {
        int e0 = g + (j << 3);
        int u0 = __shfl(idx, e0, 64);
        uint4 p0 = gin[(size_t)u0 * 8 + l];
        if (e0 < dcap) acc_bf16x8(p0, acc);
    }
    for (int i = beg + 64 + g; i < end; i += 8) {   // deg>64: essentially never
        acc_bf16x8(gin[(size_t)csr[i] * 8 + l], acc);
    }

    #pragma unroll
    for (int m = 8; m <= 32; m <<= 1) {
        #pragma unroll
        for (int jj = 0; jj < 8; ++jj) acc[jj] += __shfl_xor(acc[jj], m, 64);
    }

    float nv = norm[node];
    float h[8];
    #pragma unroll
    for (int jj = 0; jj < 8; ++jj) h[jj] = acc[jj] * nv;

    const float4* s4 = (const float4*)s;
    float4 a = s4[2 * l], b = s4[2 * l + 1];
    float dot = h[0] * a.x + h[1] * a.y + h[2] * a.z + h[3] * a.w
              + h[4] * b.x + h[5] * b.y + h[6] * b.z + h[7] * b.w;
    #pragma unroll
    for (int m = 1; m <= 4; m <<= 1) dot += __shfl_xor(dot, m, 64);
    float sig = 1.0f / (1.0f + expf(-dot));

    if (g == 0) {
        float gv[8];
        #pragma unroll
        for (int jj = 0; jj < 8; ++jj) gv[jj] = h[jj] * nv;
        gout[node * 8 + l] = pack_bf16x8(gv);
        float4 o0 = out[node * 16 + 2 * l];
        float4 o1 = out[node * 16 + 2 * l + 1];
        o0.x += sig * h[0]; o0.y += sig * h[1]; o0.z += sig * h[2]; o0.w += sig * h[3];
        o1.x += sig * h[4]; o1.y += sig * h[5]; o1.z += sig * h[6]; o1.w += sig * h[7];
        out[node * 16 + 2 * l]     = o0;
        out[node * 16 + 2 * l + 1] = o1;
    }
}

// ---- launcher -----------------------------------------------------------

extern "C" void kernel_launch(void* const* d_in, const int* in_sizes, int n_in,
                              void* d_out, int out_size, void* d_ws, size_t ws_size,
                              hipStream_t stream) {
    const float* feat = (const float*)d_in[0];
    const float* s    = (const float*)d_in[1];
    const int*   src  = (const int*)d_in[2];
    const int*   dst  = (const int*)d_in[3];
    const int K = 10;

    int N = in_sizes[0] / D;
    int E = in_sizes[2];
    int nchunks = (N + 1023) / 1024;       // 98
    int NR   = (N + RB - 1) / RB;          // 49 ranges
    int NBLK = (E + EB - 1) / EB;          // 782 edge blocks
    int M    = NR * NBLK;                  // 38318 multisplit counters
    int nchA = (M + 1023) / 1024;          // 38

    // workspace layout
    int*   counts   = (int*)d_ws;                  // N
    int*   offsets  = counts + N;                  // N+1
    int*   csr      = offsets + (N + 1);           // E
    float* norm     = (float*)(csr + E);           // N
    int*   bsum     = (int*)(norm + N);            // nchunks
    int*   countsA  = bsum + nchunks;              // M
    int*   baseA    = countsA + M;                 // M
    int*   bsumA    = baseA + M;                   // nchA
    uintptr_t p = (uintptr_t)(bsumA + nchA);
    p = (p + 255) & ~(uintptr_t)255;
    uint4* g0 = (uint4*)p;                         // N*8 uint4 (bf16 rows)
    uint4* g1 = g0 + (size_t)N * 8;                // N*8 uint4
    // ebuf2 (E u32 = 6.4MB) aliases g1 (12.8MB): consumed by passB before
    // the first spmm writes g1.
    unsigned int* ebuf2 = (unsigned int*)g1;

    hipMemsetAsync(counts, 0, sizeof(int) * (size_t)N, stream);

    // degrees -> offsets + norm
    count_edges<<<(E + 255) / 256, 256, 0, stream>>>(dst, counts, E);
    block_sums<<<nchunks, 256, 0, stream>>>(counts, bsum, N);
    scan_bsums<<<1, 1024, 0, stream>>>(bsum, nchunks, offsets, N);
    scan_block<<<nchunks, 1024, 0, stream>>>(counts, bsum, offsets, norm, N);

    // multisplit CSR build
    countA<<<NBLK, 256, 0, stream>>>(dst, countsA, E, NR, NBLK);
    block_sums<<<nchA, 256, 0, stream>>>(countsA, bsumA, M);
    scan_bsums<<<1, 1024, 0, stream>>>(bsumA, nchA, (int*)nullptr, 0);
    gen_scan2<<<nchA, 1024, 0, stream>>>(countsA, bsumA, baseA, M);
    passA2<<<NBLK, 256, 0, stream>>>(src, dst, baseA, ebuf2, E, NR, NBLK);
    passB<<<NR, 1024, 0, stream>>>(ebuf2, offsets, csr, N);

    // hops
    hop0<<<(N * 8 + 255) / 256, 256, 0, stream>>>(
        (const float4*)feat, s, norm, g0, (float4*)d_out, N);

    uint4* gin = g0; uint4* gout = g1;
    for (int t = 0; t < K; ++t) {
        spmm_hop<<<(N + 3) / 4, 256, 0, stream>>>(
            gin, offsets, csr, norm, s, gout, (float4*)d_out, N);
        uint4* tmp = gin; gin = gout; gout = tmp;
    }
}

// Round 8
// 576.809 us; speedup vs baseline: 1.7202x; 1.1454x over previous
//
#include <hip/hip_runtime.h>
#include <math.h>

#define D 64
#define RB 1024          // nodes per range (must match >>10 / &1023 below)
#define EB 2048          // edges per partition block
#define NRMAX 128        // static LDS sizing; NR = ceil(N/RB) must be <= NRMAX

// ---- helpers ------------------------------------------------------------

__device__ __forceinline__ float4 f4scale(float4 a, float b) {
    return make_float4(a.x * b, a.y * b, a.z * b, a.w * b);
}

__device__ __forceinline__ unsigned int bf16_rne(float x) {
    unsigned int u = __float_as_uint(x);
    u += 0x7fffu + ((u >> 16) & 1u);
    return u >> 16;
}

__device__ __forceinline__ uint4 pack_bf16x8(const float* v) {
    uint4 p;
    p.x = bf16_rne(v[0]) | (bf16_rne(v[1]) << 16);
    p.y = bf16_rne(v[2]) | (bf16_rne(v[3]) << 16);
    p.z = bf16_rne(v[4]) | (bf16_rne(v[5]) << 16);
    p.w = bf16_rne(v[6]) | (bf16_rne(v[7]) << 16);
    return p;
}

__device__ __forceinline__ void acc_bf16x8(uint4 p, float* a) {
    a[0] += __uint_as_float(p.x << 16);
    a[1] += __uint_as_float(p.x & 0xffff0000u);
    a[2] += __uint_as_float(p.y << 16);
    a[3] += __uint_as_float(p.y & 0xffff0000u);
    a[4] += __uint_as_float(p.z << 16);
    a[5] += __uint_as_float(p.z & 0xffff0000u);
    a[6] += __uint_as_float(p.w << 16);
    a[7] += __uint_as_float(p.w & 0xffff0000u);
}

// ---- multisplit CSR build (no global atomics anywhere) ------------------
// NR ranges of RB nodes; NBLK blocks of EB edges.

// phase 1: per-(block,range) histogram via LDS atomics
__global__ void countA(const int* __restrict__ dst, int* __restrict__ countsA_T,
                       int E, int NR, int NBLK) {
    __shared__ int hist[NRMAX];
    int t = threadIdx.x;
    for (int i = t; i < NR; i += 256) hist[i] = 0;
    __syncthreads();
    int base = blockIdx.x * EB + t;
    #pragma unroll
    for (int j = 0; j < EB / 256; ++j) {
        int e = base + j * 256;
        if (e < E) atomicAdd(&hist[dst[e] >> 10], 1);
    }
    __syncthreads();
    for (int i = t; i < NR; i += 256) countsA_T[i * NBLK + blockIdx.x] = hist[i];
}

// scan helpers for the NR x NBLK counter array (range-major)
__global__ void block_sums(const int* __restrict__ arr, int* __restrict__ bsum, int n) {
    int base = blockIdx.x * 1024;
    int t = threadIdx.x;
    int v = 0;
    #pragma unroll
    for (int j = 0; j < 4; ++j) {
        int i = base + t + j * 256;
        if (i < n) v += arr[i];
    }
    #pragma unroll
    for (int m = 32; m >= 1; m >>= 1) v += __shfl_xor(v, m, 64);
    __shared__ int ws[4];
    if ((t & 63) == 0) ws[t >> 6] = v;
    __syncthreads();
    if (t == 0) bsum[blockIdx.x] = ws[0] + ws[1] + ws[2] + ws[3];
}

__global__ void scan_bsums(int* __restrict__ bsum, int nb) {
    __shared__ int tmp[1024];
    int t = threadIdx.x;
    int v = (t < nb) ? bsum[t] : 0;
    tmp[t] = v;
    __syncthreads();
    for (int off = 1; off < 1024; off <<= 1) {
        int x = (t >= off) ? tmp[t - off] : 0;
        __syncthreads();
        tmp[t] += x;
        __syncthreads();
    }
    if (t < nb) bsum[t] = tmp[t] - v;
}

__global__ void gen_scan2(const int* __restrict__ arr, const int* __restrict__ bsum,
                          int* __restrict__ out, int n) {
    __shared__ int tmp[1024];
    int base = blockIdx.x * 1024;
    int t = threadIdx.x;
    int i = base + t;
    int v = (i < n) ? arr[i] : 0;
    tmp[t] = v;
    __syncthreads();
    for (int off = 1; off < 1024; off <<= 1) {
        int x = (t >= off) ? tmp[t - off] : 0;
        __syncthreads();
        tmp[t] += x;
        __syncthreads();
    }
    if (i < n) out[i] = bsum[blockIdx.x] + tmp[t] - v;
}

// phase 2: place (src | dst_local<<17) into range-partitioned ebuf2.
// LDS cursors seeded from scanned bases; contiguous line-local writes.
__global__ void passA2(const int* __restrict__ src, const int* __restrict__ dst,
                       const int* __restrict__ baseA, unsigned int* __restrict__ ebuf2,
                       int E, int NR, int NBLK) {
    __shared__ int cur[NRMAX];
    int t = threadIdx.x;
    for (int i = t; i < NR; i += 256) cur[i] = baseA[i * NBLK + blockIdx.x];
    __syncthreads();
    int base = blockIdx.x * EB + t;
    #pragma unroll
    for (int j = 0; j < EB / 256; ++j) {
        int e = base + j * 256;
        if (e < E) {
            int v = dst[e];
            int pos = atomicAdd(&cur[v >> 10], 1);
            ebuf2[pos] = (unsigned int)src[e] | ((unsigned int)(v & (RB - 1)) << 17);
        }
    }
}

// phase 3 (fused): per range — LDS degree histogram from ebuf2, local scan,
// write offsets+norm coalesced, place csr. Replaces count_edges + 3 scan
// kernels + passB. Zero global atomics; every csr line written by one block
// in a tight window (writeback ~= payload).
__global__ void range_build(const unsigned int* __restrict__ ebuf2,
                            const int* __restrict__ baseA,
                            int* __restrict__ offsets, float* __restrict__ norm,
                            int* __restrict__ csr, int N, int E, int NR, int NBLK) {
    __shared__ int cnt[RB];      // histogram, then absolute cursors
    __shared__ int sc[RB];       // inclusive scan workspace
    int rg = blockIdx.x;
    int t = threadIdx.x;         // 1024 threads, 1 node/thread
    int r0 = baseA[rg * NBLK];
    int r1 = (rg + 1 < NR) ? baseA[(rg + 1) * NBLK] : E;
    cnt[t] = 0;
    __syncthreads();
    for (int i = r0 + t; i < r1; i += RB)
        atomicAdd(&cnt[ebuf2[i] >> 17], 1);
    __syncthreads();
    int v = cnt[t];
    sc[t] = v;
    __syncthreads();
    for (int off = 1; off < RB; off <<= 1) {
        int x = (t >= off) ? sc[t - off] : 0;
        __syncthreads();
        sc[t] += x;
        __syncthreads();
    }
    int excl = sc[t] - v;
    int node = rg * RB + t;
    if (node < N) {
        offsets[node] = r0 + excl;
        norm[node] = rsqrtf((float)(v > 1 ? v : 1));
    }
    if (rg == NR - 1 && t == 0) offsets[N] = E;
    __syncthreads();
    cnt[t] = r0 + excl;          // absolute cursor
    __syncthreads();
    for (int i = r0 + t; i < r1; i += RB) {
        unsigned int u = ebuf2[i];
        int pos = atomicAdd(&cnt[u >> 17], 1);
        csr[pos] = (int)(u & 0x1FFFFu);
    }
}

// ---- hop 0: out = sigmoid(f.s)*f ; g0 = bf16(f*norm) --------------------

__global__ void hop0(const float4* __restrict__ feat, const float* __restrict__ s,
                     const float* __restrict__ norm, uint4* __restrict__ g,
                     float4* __restrict__ out, int n) {
    int t = blockIdx.x * blockDim.x + threadIdx.x;
    int node = t >> 3;
    int l = t & 7;
    if (node >= n) return;
    float4 f0 = feat[node * 16 + 2 * l];
    float4 f1 = feat[node * 16 + 2 * l + 1];
    const float4* s4 = (const float4*)s;
    float4 a = s4[2 * l], b = s4[2 * l + 1];
    float dot = f0.x * a.x + f0.y * a.y + f0.z * a.z + f0.w * a.w
              + f1.x * b.x + f1.y * b.y + f1.z * b.z + f1.w * b.w;
    #pragma unroll
    for (int m = 1; m <= 4; m <<= 1) dot += __shfl_xor(dot, m, 64);
    float sig = 1.0f / (1.0f + expf(-dot));
    out[node * 16 + 2 * l]     = f4scale(f0, sig);
    out[node * 16 + 2 * l + 1] = f4scale(f1, sig);
    float nv = norm[node];
    float v[8] = {f0.x * nv, f0.y * nv, f0.z * nv, f0.w * nv,
                  f1.x * nv, f1.y * nv, f1.z * nv, f1.w * nv};
    g[node * 8 + l] = pack_bf16x8(v);
}

// ---- hop t: gather-SpMM (bf16 rows) + fused attention-pool epilogue -----
// wave per node; lane = 8*g + l. 4-deep gather issue: all 4 row-loads in
// flight before one wait (deg<=32 => single memory round-trip). Shuffles
// always full-exec, in-range source lanes (g+24 <= 31, g+56 <= 63).
// Predicated-off slots read L1-hot row 0.

__global__ void spmm_hop(const uint4* __restrict__ gin, const int* __restrict__ offsets,
                         const int* __restrict__ csr, const float* __restrict__ norm,
                         const float* __restrict__ s, uint4* __restrict__ gout,
                         float4* __restrict__ out, int n) {
    int lane = threadIdx.x & 63;
    int node = blockIdx.x * 4 + (threadIdx.x >> 6);
    if (node >= n) return;          // wave-uniform exit
    int g = lane >> 3;
    int l = lane & 7;
    int beg = offsets[node], end = offsets[node + 1];
    int deg = end - beg;
    int dcap = deg < 64 ? deg : 64;
    int idx = (lane < dcap) ? csr[beg + lane] : 0;

    float acc[8] = {0.f, 0.f, 0.f, 0.f, 0.f, 0.f, 0.f, 0.f};
    {
        int e0 = g, e1 = g + 8, e2 = g + 16, e3 = g + 24;
        int u0 = __shfl(idx, e0, 64);
        int u1 = __shfl(idx, e1, 64);
        int u2 = __shfl(idx, e2, 64);
        int u3 = __shfl(idx, e3, 64);
        uint4 p0 = gin[(size_t)u0 * 8 + l];
        uint4 p1 = gin[(size_t)u1 * 8 + l];
        uint4 p2 = gin[(size_t)u2 * 8 + l];
        uint4 p3 = gin[(size_t)u3 * 8 + l];
        if (e0 < dcap) acc_bf16x8(p0, acc);
        if (e1 < dcap) acc_bf16x8(p1, acc);
        if (e2 < dcap) acc_bf16x8(p2, acc);
        if (e3 < dcap) acc_bf16x8(p3, acc);
    }
    if (dcap > 32) {                 // wave-uniform branch
        int e0 = g + 32, e1 = g + 40, e2 = g + 48, e3 = g + 56;
        int u0 = __shfl(idx, e0, 64);
        int u1 = __shfl(idx, e1, 64);
        int u2 = __shfl(idx, e2, 64);
        int u3 = __shfl(idx, e3, 64);
        uint4 p0 = gin[(size_t)u0 * 8 + l];
        uint4 p1 = gin[(size_t)u1 * 8 + l];
        uint4 p2 = gin[(size_t)u2 * 8 + l];
        uint4 p3 = gin[(size_t)u3 * 8 + l];
        if (e0 < dcap) acc_bf16x8(p0, acc);
        if (e1 < dcap) acc_bf16x8(p1, acc);
        if (e2 < dcap) acc_bf16x8(p2, acc);
        if (e3 < dcap) acc_bf16x8(p3, acc);
    }
    for (int i = beg + 64 + g; i < end; i += 8) {   // deg>64: essentially never
        acc_bf16x8(gin[(size_t)csr[i] * 8 + l], acc);
    }

    #pragma unroll
    for (int m = 8; m <= 32; m <<= 1) {
        #pragma unroll
        for (int jj = 0; jj < 8; ++jj) acc[jj] += __shfl_xor(acc[jj], m, 64);
    }

    float nv = norm[node];
    float h[8];
    #pragma unroll
    for (int jj = 0; jj < 8; ++jj) h[jj] = acc[jj] * nv;

    const float4* s4 = (const float4*)s;
    float4 a = s4[2 * l], b = s4[2 * l + 1];
    float dot = h[0] * a.x + h[1] * a.y + h[2] * a.z + h[3] * a.w
              + h[4] * b.x + h[5] * b.y + h[6] * b.z + h[7] * b.w;
    #pragma unroll
    for (int m = 1; m <= 4; m <<= 1) dot += __shfl_xor(dot, m, 64);
    float sig = 1.0f / (1.0f + expf(-dot));

    if (g == 0) {
        float gv[8];
        #pragma unroll
        for (int jj = 0; jj < 8; ++jj) gv[jj] = h[jj] * nv;
        gout[node * 8 + l] = pack_bf16x8(gv);
        float4 o0 = out[node * 16 + 2 * l];
        float4 o1 = out[node * 16 + 2 * l + 1];
        o0.x += sig * h[0]; o0.y += sig * h[1]; o0.z += sig * h[2]; o0.w += sig * h[3];
        o1.x += sig * h[4]; o1.y += sig * h[5]; o1.z += sig * h[6]; o1.w += sig * h[7];
        out[node * 16 + 2 * l]     = o0;
        out[node * 16 + 2 * l + 1] = o1;
    }
}

// ---- launcher -----------------------------------------------------------

extern "C" void kernel_launch(void* const* d_in, const int* in_sizes, int n_in,
                              void* d_out, int out_size, void* d_ws, size_t ws_size,
                              hipStream_t stream) {
    const float* feat = (const float*)d_in[0];
    const float* s    = (const float*)d_in[1];
    const int*   src  = (const int*)d_in[2];
    const int*   dst  = (const int*)d_in[3];
    const int K = 10;

    int N = in_sizes[0] / D;
    int E = in_sizes[2];
    int NR   = (N + RB - 1) / RB;          // 98 ranges  (<= NRMAX)
    int NBLK = (E + EB - 1) / EB;          // 782 edge blocks
    int M    = NR * NBLK;                  // 76636 multisplit counters
    int nchA = (M + 1023) / 1024;          // 75

    // workspace layout (no memsets needed: every buffer fully written before read)
    int*   offsets  = (int*)d_ws;                  // N+1
    int*   csr      = offsets + (N + 1);           // E
    float* norm     = (float*)(csr + E);           // N
    int*   countsA  = (int*)(norm + N);            // M
    int*   baseA    = countsA + M;                 // M
    int*   bsumA    = baseA + M;                   // nchA
    uintptr_t p = (uintptr_t)(bsumA + nchA);
    p = (p + 255) & ~(uintptr_t)255;
    uint4* g0 = (uint4*)p;                         // N*8 uint4 (bf16 rows)
    uint4* g1 = g0 + (size_t)N * 8;                // N*8 uint4
    // ebuf2 (E u32 = 6.4MB) aliases g1 (12.8MB): consumed by range_build
    // before the first spmm writes g1.
    unsigned int* ebuf2 = (unsigned int*)g1;

    // multisplit CSR build (zero global atomics)
    countA<<<NBLK, 256, 0, stream>>>(dst, countsA, E, NR, NBLK);
    block_sums<<<nchA, 256, 0, stream>>>(countsA, bsumA, M);
    scan_bsums<<<1, 1024, 0, stream>>>(bsumA, nchA);
    gen_scan2<<<nchA, 1024, 0, stream>>>(countsA, bsumA, baseA, M);
    passA2<<<NBLK, 256, 0, stream>>>(src, dst, baseA, ebuf2, E, NR, NBLK);
    range_build<<<NR, RB, 0, stream>>>(ebuf2, baseA, offsets, norm, csr, N, E, NR, NBLK);

    // hops
    hop0<<<(N * 8 + 255) / 256, 256, 0, stream>>>(
        (const float4*)feat, s, norm, g0, (float4*)d_out, N);

    uint4* gin = g0; uint4* gout = g1;
    for (int t = 0; t < K; ++t) {
        spmm_hop<<<(N + 3) / 4, 256, 0, stream>>>(
            gin, offsets, csr, norm, s, gout, (float4*)d_out, N);
        uint4* tmp = gin; gin = gout; gout = tmp;
    }
}

// Round 10
// 526.692 us; speedup vs baseline: 1.8839x; 1.0952x over previous
//
#include <hip/hip_runtime.h>
#include <hip/hip_fp16.h>
#include <math.h>

#define D 64
#define RB 1024          // nodes per range (must match >>10 / &1023 below)
#define EB 2048          // edges per partition block
#define NRMAX 128        // static LDS sizing; NR = ceil(N/RB) must be <= NRMAX
#define KHOPS 10

// ---- helpers ------------------------------------------------------------

typedef union { uint4 u; __half2 h[4]; } U4H;

// ---- multisplit CSR build (no global atomics anywhere) ------------------

__global__ void countA(const int* __restrict__ dst, int* __restrict__ countsA_T,
                       int E, int NR, int NBLK) {
    __shared__ int hist[NRMAX];
    int t = threadIdx.x;
    for (int i = t; i < NR; i += 256) hist[i] = 0;
    __syncthreads();
    int base = blockIdx.x * EB + t;
    #pragma unroll
    for (int j = 0; j < EB / 256; ++j) {
        int e = base + j * 256;
        if (e < E) atomicAdd(&hist[dst[e] >> 10], 1);
    }
    __syncthreads();
    for (int i = t; i < NR; i += 256) countsA_T[i * NBLK + blockIdx.x] = hist[i];
}

__global__ void block_sums(const int* __restrict__ arr, int* __restrict__ bsum, int n) {
    int base = blockIdx.x * 1024;
    int t = threadIdx.x;
    int v = 0;
    #pragma unroll
    for (int j = 0; j < 4; ++j) {
        int i = base + t + j * 256;
        if (i < n) v += arr[i];
    }
    #pragma unroll
    for (int m = 32; m >= 1; m >>= 1) v += __shfl_xor(v, m, 64);
    __shared__ int ws[4];
    if ((t & 63) == 0) ws[t >> 6] = v;
    __syncthreads();
    if (t == 0) bsum[blockIdx.x] = ws[0] + ws[1] + ws[2] + ws[3];
}

__global__ void scan_bsums(int* __restrict__ bsum, int nb) {
    __shared__ int tmp[1024];
    int t = threadIdx.x;
    int v = (t < nb) ? bsum[t] : 0;
    tmp[t] = v;
    __syncthreads();
    for (int off = 1; off < 1024; off <<= 1) {
        int x = (t >= off) ? tmp[t - off] : 0;
        __syncthreads();
        tmp[t] += x;
        __syncthreads();
    }
    if (t < nb) bsum[t] = tmp[t] - v;
}

__global__ void gen_scan2(const int* __restrict__ arr, const int* __restrict__ bsum,
                          int* __restrict__ out, int n) {
    __shared__ int tmp[1024];
    int base = blockIdx.x * 1024;
    int t = threadIdx.x;
    int i = base + t;
    int v = (i < n) ? arr[i] : 0;
    tmp[t] = v;
    __syncthreads();
    for (int off = 1; off < 1024; off <<= 1) {
        int x = (t >= off) ? tmp[t - off] : 0;
        __syncthreads();
        tmp[t] += x;
        __syncthreads();
    }
    if (i < n) out[i] = bsum[blockIdx.x] + tmp[t] - v;
}

__global__ void passA2(const int* __restrict__ src, const int* __restrict__ dst,
                       const int* __restrict__ baseA, unsigned int* __restrict__ ebuf2,
                       int E, int NR, int NBLK) {
    __shared__ int cur[NRMAX];
    int t = threadIdx.x;
    for (int i = t; i < NR; i += 256) cur[i] = baseA[i * NBLK + blockIdx.x];
    __syncthreads();
    int base = blockIdx.x * EB + t;
    #pragma unroll
    for (int j = 0; j < EB / 256; ++j) {
        int e = base + j * 256;
        if (e < E) {
            int v = dst[e];
            int pos = atomicAdd(&cur[v >> 10], 1);
            ebuf2[pos] = (unsigned int)src[e] | ((unsigned int)(v & (RB - 1)) << 17);
        }
    }
}

__global__ void range_build(const unsigned int* __restrict__ ebuf2,
                            const int* __restrict__ baseA,
                            int* __restrict__ offsets, float* __restrict__ norm,
                            int* __restrict__ csr, int N, int E, int NR, int NBLK) {
    __shared__ int cnt[RB];
    __shared__ int sc[RB];
    int rg = blockIdx.x;
    int t = threadIdx.x;
    int r0 = baseA[rg * NBLK];
    int r1 = (rg + 1 < NR) ? baseA[(rg + 1) * NBLK] : E;
    cnt[t] = 0;
    __syncthreads();
    for (int i = r0 + t; i < r1; i += RB)
        atomicAdd(&cnt[ebuf2[i] >> 17], 1);
    __syncthreads();
    int v = cnt[t];
    sc[t] = v;
    __syncthreads();
    for (int off = 1; off < RB; off <<= 1) {
        int x = (t >= off) ? sc[t - off] : 0;
        __syncthreads();
        sc[t] += x;
        __syncthreads();
    }
    int excl = sc[t] - v;
    int node = rg * RB + t;
    if (node < N) {
        offsets[node] = r0 + excl;
        norm[node] = rsqrtf((float)(v > 1 ? v : 1));
    }
    if (rg == NR - 1 && t == 0) offsets[N] = E;
    __syncthreads();
    cnt[t] = r0 + excl;
    __syncthreads();
    for (int i = r0 + t; i < r1; i += RB) {
        unsigned int u = ebuf2[i];
        int pos = atomicAdd(&cnt[u >> 17], 1);
        csr[pos] = (int)(u & 0x1FFFFu);
    }
}

// ---- hop 0: g0 = f16(f*norm); if do_pool also out = sigmoid(f.s)*f ------
// 8 lanes per node, 8 dims (2 float4) per lane.

__global__ void hop0(const float4* __restrict__ feat, const float* __restrict__ s,
                     const float* __restrict__ norm, uint4* __restrict__ g0,
                     float4* __restrict__ out, int n, int do_pool) {
    int t = blockIdx.x * blockDim.x + threadIdx.x;
    int node = t >> 3;
    int l = t & 7;
    if (node >= n) return;
    float4 f0 = feat[node * 16 + 2 * l];
    float4 f1 = feat[node * 16 + 2 * l + 1];
    float nv = norm[node];
    U4H P;
    P.h[0] = __floats2half2_rn(f0.x * nv, f0.y * nv);
    P.h[1] = __floats2half2_rn(f0.z * nv, f0.w * nv);
    P.h[2] = __floats2half2_rn(f1.x * nv, f1.y * nv);
    P.h[3] = __floats2half2_rn(f1.z * nv, f1.w * nv);
    g0[node * 8 + l] = P.u;
    if (do_pool) {
        const float4* s4 = (const float4*)s;
        float4 a = s4[2 * l], b = s4[2 * l + 1];
        float dot = f0.x * a.x + f0.y * a.y + f0.z * a.z + f0.w * a.w
                  + f1.x * b.x + f1.y * b.y + f1.z * b.z + f1.w * b.w;
        #pragma unroll
        for (int m = 1; m <= 4; m <<= 1) dot += __shfl_xor(dot, m, 64);
        float sig = 1.0f / (1.0f + expf(-dot));
        out[node * 16 + 2 * l]     = make_float4(sig * f0.x, sig * f0.y, sig * f0.z, sig * f0.w);
        out[node * 16 + 2 * l + 1] = make_float4(sig * f1.x, sig * f1.y, sig * f1.z, sig * f1.w);
    }
}

// ---- hop t: gather-SpMM (f16 rows, packed-f16 accumulate) ---------------
// wave per node; lane = 8*g + l. Divergence-free shuffles; 4-deep gather
// issue. Packed __hadd2 accumulate (v_pk_add_f16): 4 VALU/edge vs 16 for
// bf16 unpack; <=8 f16 adds per lane before f32 conversion keeps error tiny.

__global__ void spmm_hop(const uint4* __restrict__ gin, const int* __restrict__ offsets,
                         const int* __restrict__ csr, const float* __restrict__ norm,
                         const float* __restrict__ s, uint4* __restrict__ gout,
                         float4* __restrict__ out, int n, int do_pool, int write_g) {
    int lane = threadIdx.x & 63;
    int node = blockIdx.x * 4 + (threadIdx.x >> 6);
    if (node >= n) return;          // wave-uniform exit
    int g = lane >> 3;
    int l = lane & 7;
    int beg = offsets[node], end = offsets[node + 1];
    int deg = end - beg;
    int dcap = deg < 64 ? deg : 64;
    int idx = (lane < dcap) ? csr[beg + lane] : 0;

    __half2 z = __floats2half2_rn(0.f, 0.f);
    __half2 ah0 = z, ah1 = z, ah2 = z, ah3 = z;
    {
        int e0 = g, e1 = g + 8, e2 = g + 16, e3 = g + 24;
        int u0 = __shfl(idx, e0, 64);
        int u1 = __shfl(idx, e1, 64);
        int u2 = __shfl(idx, e2, 64);
        int u3 = __shfl(idx, e3, 64);
        U4H A, B, C, Dd;
        A.u = gin[(size_t)u0 * 8 + l];
        B.u = gin[(size_t)u1 * 8 + l];
        C.u = gin[(size_t)u2 * 8 + l];
        Dd.u = gin[(size_t)u3 * 8 + l];
        if (e0 < dcap) { ah0 = __hadd2(ah0, A.h[0]); ah1 = __hadd2(ah1, A.h[1]); ah2 = __hadd2(ah2, A.h[2]); ah3 = __hadd2(ah3, A.h[3]); }
        if (e1 < dcap) { ah0 = __hadd2(ah0, B.h[0]); ah1 = __hadd2(ah1, B.h[1]); ah2 = __hadd2(ah2, B.h[2]); ah3 = __hadd2(ah3, B.h[3]); }
        if (e2 < dcap) { ah0 = __hadd2(ah0, C.h[0]); ah1 = __hadd2(ah1, C.h[1]); ah2 = __hadd2(ah2, C.h[2]); ah3 = __hadd2(ah3, C.h[3]); }
        if (e3 < dcap) { ah0 = __hadd2(ah0, Dd.h[0]); ah1 = __hadd2(ah1, Dd.h[1]); ah2 = __hadd2(ah2, Dd.h[2]); ah3 = __hadd2(ah3, Dd.h[3]); }
    }
    if (dcap > 32) {                 // wave-uniform branch
        int e0 = g + 32, e1 = g + 40, e2 = g + 48, e3 = g + 56;
        int u0 = __shfl(idx, e0, 64);
        int u1 = __shfl(idx, e1, 64);
        int u2 = __shfl(idx, e2, 64);
        int u3 = __shfl(idx, e3, 64);
        U4H A, B, C, Dd;
        A.u = gin[(size_t)u0 * 8 + l];
        B.u = gin[(size_t)u1 * 8 + l];
        C.u = gin[(size_t)u2 * 8 + l];
        Dd.u = gin[(size_t)u3 * 8 + l];
        if (e0 < dcap) { ah0 = __hadd2(ah0, A.h[0]); ah1 = __hadd2(ah1, A.h[1]); ah2 = __hadd2(ah2, A.h[2]); ah3 = __hadd2(ah3, A.h[3]); }
        if (e1 < dcap) { ah0 = __hadd2(ah0, B.h[0]); ah1 = __hadd2(ah1, B.h[1]); ah2 = __hadd2(ah2, B.h[2]); ah3 = __hadd2(ah3, B.h[3]); }
        if (e2 < dcap) { ah0 = __hadd2(ah0, C.h[0]); ah1 = __hadd2(ah1, C.h[1]); ah2 = __hadd2(ah2, C.h[2]); ah3 = __hadd2(ah3, C.h[3]); }
        if (e3 < dcap) { ah0 = __hadd2(ah0, Dd.h[0]); ah1 = __hadd2(ah1, Dd.h[1]); ah2 = __hadd2(ah2, Dd.h[2]); ah3 = __hadd2(ah3, Dd.h[3]); }
    }

    float2 q0 = __half22float2(ah0), q1 = __half22float2(ah1);
    float2 q2 = __half22float2(ah2), q3 = __half22float2(ah3);
    float acc[8] = {q0.x, q0.y, q1.x, q1.y, q2.x, q2.y, q3.x, q3.y};

    for (int i = beg + 64 + g; i < end; i += 8) {   // deg>64: essentially never
        U4H P; P.u = gin[(size_t)csr[i] * 8 + l];
        float2 a0 = __half22float2(P.h[0]), a1 = __half22float2(P.h[1]);
        float2 a2 = __half22float2(P.h[2]), a3 = __half22float2(P.h[3]);
        acc[0] += a0.x; acc[1] += a0.y; acc[2] += a1.x; acc[3] += a1.y;
        acc[4] += a2.x; acc[5] += a2.y; acc[6] += a3.x; acc[7] += a3.y;
    }

    // reduce across the 8 edge-subgroups (lane bits 3,4,5) in f32
    #pragma unroll
    for (int m = 8; m <= 32; m <<= 1) {
        #pragma unroll
        for (int jj = 0; jj < 8; ++jj) acc[jj] += __shfl_xor(acc[jj], m, 64);
    }

    float nv = norm[node];
    float h[8];
    #pragma unroll
    for (int jj = 0; jj < 8; ++jj) h[jj] = acc[jj] * nv;

    float sig = 0.f;
    if (do_pool) {                   // wave-uniform flag
        const float4* s4 = (const float4*)s;
        float4 a = s4[2 * l], b = s4[2 * l + 1];
        float dot = h[0] * a.x + h[1] * a.y + h[2] * a.z + h[3] * a.w
                  + h[4] * b.x + h[5] * b.y + h[6] * b.z + h[7] * b.w;
        #pragma unroll
        for (int m = 1; m <= 4; m <<= 1) dot += __shfl_xor(dot, m, 64);
        sig = 1.0f / (1.0f + expf(-dot));
    }

    if (g == 0) {
        if (write_g) {
            U4H P;
            P.h[0] = __floats2half2_rn(h[0] * nv, h[1] * nv);
            P.h[1] = __floats2half2_rn(h[2] * nv, h[3] * nv);
            P.h[2] = __floats2half2_rn(h[4] * nv, h[5] * nv);
            P.h[3] = __floats2half2_rn(h[6] * nv, h[7] * nv);
            gout[node * 8 + l] = P.u;
        }
        if (do_pool) {
            float4 o0 = out[node * 16 + 2 * l];
            float4 o1 = out[node * 16 + 2 * l + 1];
            o0.x += sig * h[0]; o0.y += sig * h[1]; o0.z += sig * h[2]; o0.w += sig * h[3];
            o1.x += sig * h[4]; o1.y += sig * h[5]; o1.z += sig * h[6]; o1.w += sig * h[7];
            out[node * 16 + 2 * l]     = o0;
            out[node * 16 + 2 * l + 1] = o1;
        }
    }
}

// ---- deferred pooling epilogue ------------------------------------------
// out = sum_t sigmoid((g_t . s)/nv) * g_t / nv   over t=0..KHOPS
// (g_t = h_t * nv, with h_0 = features). One streaming pass, out written once.

__global__ void pool_epilogue(const uint4* __restrict__ gbase, size_t gstride,
                              const float* __restrict__ norm,
                              const float* __restrict__ s,
                              float4* __restrict__ out, int N) {
    int t0 = blockIdx.x * blockDim.x + threadIdx.x;
    int node = t0 >> 3;
    int l = t0 & 7;
    if (node >= N) return;          // uniform per 8-lane group
    float inv_nv = 1.0f / norm[node];
    const float4* s4 = (const float4*)s;
    float4 sa = s4[2 * l], sb = s4[2 * l + 1];
    float o[8] = {0.f, 0.f, 0.f, 0.f, 0.f, 0.f, 0.f, 0.f};
    for (int t = 0; t <= KHOPS; ++t) {
        U4H P; P.u = gbase[(size_t)t * gstride + (size_t)node * 8 + l];
        float2 a0 = __half22float2(P.h[0]), a1 = __half22float2(P.h[1]);
        float2 a2 = __half22float2(P.h[2]), a3 = __half22float2(P.h[3]);
        float gf[8] = {a0.x, a0.y, a1.x, a1.y, a2.x, a2.y, a3.x, a3.y};
        float dot = gf[0] * sa.x + gf[1] * sa.y + gf[2] * sa.z + gf[3] * sa.w
                  + gf[4] * sb.x + gf[5] * sb.y + gf[6] * sb.z + gf[7] * sb.w;
        #pragma unroll
        for (int m = 1; m <= 4; m <<= 1) dot += __shfl_xor(dot, m, 64);
        float sig = 1.0f / (1.0f + expf(-dot * inv_nv));
        float sc = sig * inv_nv;
        #pragma unroll
        for (int j = 0; j < 8; ++j) o[j] += sc * gf[j];
    }
    out[node * 16 + 2 * l]     = make_float4(o[0], o[1], o[2], o[3]);
    out[node * 16 + 2 * l + 1] = make_float4(o[4], o[5], o[6], o[7]);
}

// ---- launcher -----------------------------------------------------------

extern "C" void kernel_launch(void* const* d_in, const int* in_sizes, int n_in,
                              void* d_out, int out_size, void* d_ws, size_t ws_size,
                              hipStream_t stream) {
    const float* feat = (const float*)d_in[0];
    const float* s    = (const float*)d_in[1];
    const int*   src  = (const int*)d_in[2];
    const int*   dst  = (const int*)d_in[3];

    int N = in_sizes[0] / D;
    int E = in_sizes[2];
    int NR   = (N + RB - 1) / RB;          // 98 ranges  (<= NRMAX)
    int NBLK = (E + EB - 1) / EB;          // 782 edge blocks
    int M    = NR * NBLK;
    int nchA = (M + 1023) / 1024;

    // fixed workspace layout
    int*   offsets  = (int*)d_ws;                  // N+1
    int*   csr      = offsets + (N + 1);           // E
    float* norm     = (float*)(csr + E);           // N
    int*   countsA  = (int*)(norm + N);            // M
    int*   baseA    = countsA + M;                 // M
    int*   bsumA    = baseA + M;                   // nchA
    uintptr_t p = (uintptr_t)(bsumA + nchA);
    p = (p + 255) & ~(uintptr_t)255;
    uint4* gbase = (uint4*)p;                      // f16 rows: N*8 uint4 per buffer
    size_t gstride = (size_t)N * 8;                // uint4 per buffer (12.8 MB)

    // deferred pooling needs KHOPS+1 g buffers; fall back to 2-buffer ping-pong
    size_t fixed_bytes = (uintptr_t)gbase - (uintptr_t)d_ws;
    int deferred = (ws_size >= fixed_bytes + (size_t)(KHOPS + 1) * gstride * sizeof(uint4)) ? 1 : 0;

    // ebuf2 (E u32 = 6.4MB) aliases g buffer #1 (first written by the first
    // spmm hop, after range_build has consumed ebuf2)
    unsigned int* ebuf2 = (unsigned int*)(gbase + gstride);

    // multisplit CSR build (zero global atomics)
    countA<<<NBLK, 256, 0, stream>>>(dst, countsA, E, NR, NBLK);
    block_sums<<<nchA, 256, 0, stream>>>(countsA, bsumA, M);
    scan_bsums<<<1, 1024, 0, stream>>>(bsumA, nchA);
    gen_scan2<<<nchA, 1024, 0, stream>>>(countsA, bsumA, baseA, M);
    passA2<<<NBLK, 256, 0, stream>>>(src, dst, baseA, ebuf2, E, NR, NBLK);
    range_build<<<NR, RB, 0, stream>>>(ebuf2, baseA, offsets, norm, csr, N, E, NR, NBLK);

    float4* outp = (float4*)d_out;
    int nb_node8 = (N * 8 + 255) / 256;
    int nb_spmm  = (N + 3) / 4;

    hop0<<<nb_node8, 256, 0, stream>>>((const float4*)feat, s, norm, gbase,
                                       outp, N, deferred ? 0 : 1);

    if (deferred) {
        for (int t = 0; t < KHOPS; ++t) {
            spmm_hop<<<nb_spmm, 256, 0, stream>>>(
                gbase + (size_t)t * gstride, offsets, csr, norm, s,
                gbase + (size_t)(t + 1) * gstride, outp, N, 0, 1);
        }
        pool_epilogue<<<nb_node8, 256, 0, stream>>>(gbase, gstride, norm, s, outp, N);
    } else {
        uint4* gin = gbase;
        uint4* gout = gbase + gstride;
        for (int t = 0; t < KHOPS; ++t) {
            spmm_hop<<<nb_spmm, 256, 0, stream>>>(
                gin, offsets, csr, norm, s, gout, outp, N, 1, (t < KHOPS - 1) ? 1 : 0);
            uint4* tmp = gin; gin = gout; gout = tmp;
        }
    }
}